// Round 14
// baseline (311.881 us; speedup 1.0000x reference)
//
#include <hip/hip_runtime.h>
#include <hip/hip_bf16.h>

// B=2, N=2048, D=1024, H=16, DH=64. Output fp32; inputs runtime-detected and
// converted once. R12: qkv/oproj staging via global_load_lds width=16 + XOR
// chunk swizzle; attn diagonal-tile specialization.
// R14/R22: attn ALiBi reach cap. R16/R18: XCD-grouped LPT schedule.
// R20/R21/R23 WINs (186.5->172.6): flash-decoding chain split (<=8 tiles) +
// exact f32 partial merge; prep fusion; cap T=24.
// R22(b) REVERTED: direct-global K/V frags = 16 cachelines/lane-load.
// R24 (neutral): 8-wave oproj kept.
// R25: (a) cap T=24->16: skipped/kept mass ~2^-12 worst-tail (concentration
// bound), absmax headroom 4x -> jcap [1,1,1,1,1,2,2,3,4,6,8,12,16,23,32,32],
// tiles 7578->6310 (0.83x); groups re-balanced {775,800,806,774}; grid 1536.
// (b) attn_merge FUSED into attn: per-item counter (zeroed by prep each
// launch), partial blocks store->threadfence->syncthreads->tid0 atomicAdd;
// last chain (old==cnt-1) fences + merges + writes AO. Removes 1 launch and
// overlaps the merge with remaining attn blocks. No spin-waits -> no
// deadlock possible (last block just does extra work).
// R26: identical resubmit of R25 (infra failure, no measurement).
//
// ws (bf16 elems): Q@0(4M), K@4M, Vt@8M, Xc/AO@12M (shared), WqT@16M..WoT@19M,
// boc@20M, partials @22M (f32) + cnt_arr. ws >= 268MB per harness.

typedef __bf16 bf16x8 __attribute__((ext_vector_type(8)));
typedef float f32x4 __attribute__((ext_vector_type(4)));
typedef short s4 __attribute__((ext_vector_type(4)));      // k16 MFMA A/B frag
typedef unsigned short ushort_t;

#define MFMA_16x16x32(a, b, c) __builtin_amdgcn_mfma_f32_16x16x32_bf16(a, b, c, 0, 0, 0)
#define MFMA16(a, b, c) __builtin_amdgcn_mfma_f32_16x16x16bf16_1k(a, b, c, 0, 0, 0)

__device__ __forceinline__ ushort_t f2bf(float f) {
    __hip_bfloat16 h = __float2bfloat16(f);
    return __builtin_bit_cast(ushort_t, h);
}
__device__ __forceinline__ float bf2f(ushort_t u) {
    unsigned x = ((unsigned)u) << 16;
    return __builtin_bit_cast(float, x);
}

// async global->LDS, 16B/lane; LDS dest = wave-uniform base + lane*16.
__device__ __forceinline__ void gl_lds16(const ushort_t* g, ushort_t* l) {
    __builtin_amdgcn_global_load_lds(
        (const __attribute__((address_space(1))) void*)g,
        (__attribute__((address_space(3))) void*)l, 16, 0, 0);
}

__device__ __forceinline__ unsigned detect_fp32(const void* wp) {
    const ushort_t* w = (const ushort_t*)wp;
    unsigned c = 0;
    #pragma unroll
    for (int i = 0; i < 128; ++i) c += (((w[i] >> 7) & 0xFF) >= 0x7F) ? 1u : 0u;
    return (c > 8) ? 1u : 0u;
}

__device__ __forceinline__ uint4 load8(const void* p, size_t idx, unsigned flag) {
    if (flag) {
        const float* f = (const float*)p + idx;
        float4 a = *(const float4*)f;
        float4 b = *(const float4*)(f + 4);
        ushort_t u[8] = { f2bf(a.x), f2bf(a.y), f2bf(a.z), f2bf(a.w),
                          f2bf(b.x), f2bf(b.y), f2bf(b.z), f2bf(b.w) };
        return *(uint4*)u;
    }
    return *(const uint4*)((const ushort_t*)p + idx);
}

// ---- R25 schedule (T=16 cap). Sub-item encoding (32b):
// bh[4:0], qb[9:5], jbeg[14:10], jend[20:15], slot[31:21] (2047 = direct).
// e==0 marks empty slot. Merge item mi: bh[4:0], qb[9:5], base[20:10],
// cnt[23:21]. s2mi[slot] -> mi index. XCD = slot%8, CU = (slot/8)%32.
// Items with w>=9 split into ceil(w/8) balanced chains (<=8 tiles).
struct Sched { unsigned v[1536]; unsigned mi[240]; unsigned short s2mi[640]; };
constexpr Sched make_sched() {
    Sched s{};
    for (int i = 0; i < 1536; ++i) s.v[i] = 0;
    for (int i = 0; i < 240; ++i) s.mi[i] = 0;
    for (int i = 0; i < 640; ++i) s.s2mi[i] = 0;
    int jc[16] = {1, 1, 1, 1, 1, 2, 2, 3, 4, 6, 8, 12, 16, 23, 32, 32};
    // groups of 4 bh, tile-sums {775,800,806,774} per batch-group (T=16)
    int grp[8][4] = {
        {14, 8, 7, 0}, {15, 9, 5, 1}, {13, 10, 6, 2}, {12, 11, 4, 3},
        {16 + 14, 16 + 8, 16 + 7, 16 + 0}, {16 + 15, 16 + 9, 16 + 5, 16 + 1},
        {16 + 13, 16 + 10, 16 + 6, 16 + 2}, {16 + 12, 16 + 11, 16 + 4, 16 + 3},
    };
    int nslot = 0, nmi = 0;
    for (int x = 0; x < 8; ++x) {
        int sb_bh[256], sb_qb[256], sb_jb[256], sb_je[256], sb_sl[256];
        int n = 0;
        for (int gi = 0; gi < 4; ++gi) {
            int bh = grp[x][gi], h = bh & 15;
            for (int qb = 0; qb < 32; ++qb) {
                int w = (qb + 1 < jc[h]) ? (qb + 1) : jc[h];
                if (w >= 9) {
                    int nch = (w + 7) / 8;
                    s.mi[nmi] = (unsigned)(bh | (qb << 5) | (nslot << 10) | (nch << 21));
                    int jb = 0;
                    for (int c = 0; c < nch; ++c) {
                        int je = jb + (w - jb) / (nch - c)
                               + (((w - jb) % (nch - c)) ? 1 : 0);
                        s.s2mi[nslot] = (unsigned short)nmi;
                        sb_bh[n] = bh; sb_qb[n] = qb; sb_jb[n] = jb;
                        sb_je[n] = je; sb_sl[n] = nslot++; ++n;
                        jb = je;
                    }
                    ++nmi;
                } else {
                    sb_bh[n] = bh; sb_qb[n] = qb; sb_jb[n] = 0;
                    sb_je[n] = w; sb_sl[n] = 2047; ++n;
                }
            }
        }
        int m = 0;
        for (int w = 8; w >= 1; --w)                    // counting sort, desc len
            for (int i2 = 0; i2 < n; ++i2)
                if (sb_je[i2] - sb_jb[i2] == w) {
                    int t = m++;
                    int r = t >> 5, p = t & 31;
                    int cu = (r & 1) ? (31 - p) : p;    // serpentine
                    s.v[r * 256 + cu * 8 + x] = (unsigned)(
                        sb_bh[i2] | (sb_qb[i2] << 5) | (sb_jb[i2] << 10) |
                        (sb_je[i2] << 15) | (sb_sl[i2] << 21));
                }
    }
    return s;
}
__constant__ Sched g_sched = make_sched();

// ---------------- prep: convert X + bias + transpose weights + zero counters ----------------
__global__ __launch_bounds__(256) void prep(
    const void* __restrict__ X, const void* __restrict__ Wq,
    const void* __restrict__ Wk, const void* __restrict__ Wv,
    const void* __restrict__ Wo, const void* __restrict__ bo,
    ushort_t* __restrict__ Xc, ushort_t* __restrict__ boc,
    ushort_t* __restrict__ WqT, ushort_t* __restrict__ WkT,
    ushort_t* __restrict__ WvT, ushort_t* __restrict__ WoT,
    unsigned* __restrict__ cntA)
{
    __shared__ ushort_t T[64][72];
    const unsigned flag = detect_fp32(Wq);
    const int blk = blockIdx.x;
    if (blk < 2048) {
        size_t idx = (size_t)blk * 2048 + (size_t)threadIdx.x * 8;
        *(uint4*)(Xc + idx) = load8(X, idx, flag);
    } else if (blk == 2048) {
        size_t idx = (size_t)threadIdx.x * 8;
        if (idx < 1024) *(uint4*)(boc + idx) = load8(bo, idx, flag);
        if (threadIdx.x < 240) cntA[threadIdx.x] = 0;   // merge counters
    } else {
        const int t = blk - 2049;                       // 0..1023
        const int z = t >> 8;
        const void* W = (z == 0) ? Wq : ((z == 1) ? Wk : ((z == 2) ? Wv : Wo));
        ushort_t* WT = (z == 0) ? WqT : ((z == 1) ? WkT : ((z == 2) ? WvT : WoT));
        const int k0 = ((t >> 4) & 15) * 64, n0 = (t & 15) * 64;
        const int r = threadIdx.x >> 2, c = (threadIdx.x & 3) * 16;

        *(uint4*)&T[r][c]     = load8(W, (size_t)(k0 + r) * 1024 + n0 + c,     flag);
        *(uint4*)&T[r][c + 8] = load8(W, (size_t)(k0 + r) * 1024 + n0 + c + 8, flag);
        __syncthreads();
        ushort_t tmp[16];
        #pragma unroll
        for (int j = 0; j < 16; ++j) tmp[j] = T[c + j][r];
        *(uint4*)(WT + (size_t)(n0 + r) * 1024 + k0 + c)     = *(uint4*)&tmp[0];
        *(uint4*)(WT + (size_t)(n0 + r) * 1024 + k0 + c + 8) = *(uint4*)&tmp[8];
    }
}

// ---------------- QKV projection GEMM, 128x128, global_load_lds staging ----------------
__global__ __launch_bounds__(256) void qkv_gemm(
    const ushort_t* __restrict__ X, const ushort_t* __restrict__ WqT,
    const ushort_t* __restrict__ WkT, const ushort_t* __restrict__ WvT,
    ushort_t* __restrict__ Q, ushort_t* __restrict__ K, ushort_t* __restrict__ Vt)
{
    __shared__ ushort_t As[128 * 32];
    __shared__ ushort_t Bs[128 * 32];

    const int z = blockIdx.z;
    const ushort_t* WT = (z == 0) ? WqT : ((z == 1) ? WkT : WvT);

    const int tid  = threadIdx.x;
    const int m0   = blockIdx.y * 128, n0 = blockIdx.x * 128;
    const int lane = tid & 63, wv = tid >> 6;
    const int quad = lane >> 4, l15 = lane & 15;
    const int wm = (wv & 1) * 64, wn = (wv >> 1) * 64;

    const int lrow = lane >> 2;                         // 0..15
    const int schk = (lane & 3) ^ ((lane >> 3) & 3);    // swizzled source chunk
    const int ra0_ = wv * 16 + lrow;                    // issue-0 row
    ushort_t* aB0 = As + wv * 512;                      // wave-uniform LDS bases
    ushort_t* aB1 = As + 2048 + wv * 512;
    ushort_t* bB0 = Bs + wv * 512;
    ushort_t* bB1 = Bs + 2048 + wv * 512;
    const int sp = quad ^ ((l15 >> 1) & 3);             // read chunk position

    f32x4 acc[4][4] = {};

    for (int kt = 0; kt < 32; ++kt) {
        const int k0 = kt * 32;
        __syncthreads();
        gl_lds16(X  + (size_t)(m0 + ra0_)      * 1024 + k0 + schk * 8, aB0);
        gl_lds16(X  + (size_t)(m0 + 64 + ra0_) * 1024 + k0 + schk * 8, aB1);
        gl_lds16(WT + (size_t)(n0 + ra0_)      * 1024 + k0 + schk * 8, bB0);
        gl_lds16(WT + (size_t)(n0 + 64 + ra0_) * 1024 + k0 + schk * 8, bB1);
        __syncthreads();   // compiler emits vmcnt(0) drain -> LDS data visible

        bf16x8 af[4], bfr[4];
        #pragma unroll
        for (int t = 0; t < 4; ++t) {
            af[t]  = *(const bf16x8*)(As + (wm + t * 16 + l15) * 32 + sp * 8);
            bfr[t] = *(const bf16x8*)(Bs + (wn + t * 16 + l15) * 32 + sp * 8);
        }
        #pragma unroll
        for (int mt = 0; mt < 4; ++mt)
            #pragma unroll
            for (int nt = 0; nt < 4; ++nt)
                acc[mt][nt] = MFMA_16x16x32(af[mt], bfr[nt], acc[mt][nt]);
    }

    #pragma unroll
    for (int mt = 0; mt < 4; ++mt) {
        #pragma unroll
        for (int nt = 0; nt < 4; ++nt) {
            if (z == 2) {
                int c  = n0 + wn + nt * 16 + l15;
                int h  = c >> 6, dh = c & 63;
                int mA = m0 + wm + mt * 16 + quad * 4;
                int b  = mA >> 11, nseq = mA & 2047;
                ushort_t pk[4];
                #pragma unroll
                for (int r = 0; r < 4; ++r) pk[r] = f2bf(acc[mt][nt][r]);
                *(ushort2*)(Vt + ((size_t)((b * 16 + h) * 64 + dh)) * 2048 + nseq)     = *(ushort2*)&pk[0];
                *(ushort2*)(Vt + ((size_t)((b * 16 + h) * 64 + dh)) * 2048 + nseq + 2) = *(ushort2*)&pk[2];
            } else {
                ushort_t* dst = (z == 0) ? Q : K;
                #pragma unroll
                for (int r = 0; r < 4; ++r) {
                    int m = m0 + wm + mt * 16 + quad * 4 + r;
                    int c = n0 + wn + nt * 16 + l15;
                    int b = m >> 11, nseq = m & 2047;
                    int h = c >> 6, dh = c & 63;
                    dst[((size_t)((b * 16 + h) * 2048 + nseq)) * 64 + dh] = f2bf(acc[mt][nt][r]);
                }
            }
        }
    }
}

// ---------------- MFMA flash attention: LDS-staged chains + fused merge ----------------
// grid 1536 flat, block 256 = 4 waves; sub-item from g_sched. slot==2047
// writes AO directly; else writes f32 partials then atomically counts; the
// LAST chain of an item (old==cnt-1) merges all partials -> AO in-kernel.
// Partial sums are linear in j (softmax ref = j=0 globally) -> exact merge.
__global__ __launch_bounds__(256) void attn_kernel(
    const ushort_t* __restrict__ Q, const ushort_t* __restrict__ K,
    const ushort_t* __restrict__ Vt, ushort_t* __restrict__ AO,
    float* __restrict__ partV, float* __restrict__ partL,
    unsigned* __restrict__ cntA)
{
    __shared__ ushort_t Ks[64 * 72];   // [j][d], stride 72
    __shared__ ushort_t Vs[64 * 72];   // [d][j], stride 72
    __shared__ unsigned s_last;

    const unsigned e = g_sched.v[blockIdx.x];
    const int jend = (e >> 15) & 63;
    if (jend == 0) return;                              // empty slot

    const int tid  = threadIdx.x;
    const int wv   = tid >> 6, lane = tid & 63;
    const int quad = lane >> 4, l15 = lane & 15;
    const int bh   = e & 31, h = bh & 15, b = bh >> 4;
    const int qb   = (e >> 5) & 31;
    const int jbeg = (e >> 10) & 31;
    const int slot = (e >> 21) & 2047;
    const int iw   = qb * 64 + wv * 16;
    const int i_   = iw + l15;

    const ushort_t* Qh = Q  + (size_t)bh * 2048 * 64;
    const ushort_t* Kh = K  + (size_t)bh * 2048 * 64;
    const ushort_t* Vh = Vt + (size_t)bh * 64 * 2048;

    const float LOG2E = 1.44269504088896340736f;
    const float sl2 = exp2f(-0.5f * (float)(h + 1)) * LOG2E;
    const float c1  = 0.125f * LOG2E;

    bf16x8 qf0 = *(const bf16x8*)(Qh + (size_t)(iw + l15) * 64 + quad * 8);
    bf16x8 qf1 = *(const bf16x8*)(Qh + (size_t)(iw + l15) * 64 + 32 + quad * 8);

    s4 onesf;
    #pragma unroll
    for (int e2 = 0; e2 < 4; ++e2) onesf[e2] = (short)0x3F80;

    // per-lane bias base: -sl2*(quad*4+r); per-subtile only add -sl2*j0s.
    float nb[4];
    #pragma unroll
    for (int r = 0; r < 4; ++r) nb[r] = -sl2 * (float)(quad * 4 + r);

    f32x4 accv[4] = {};
    f32x4 accl = {};

    const int sr = tid >> 2, sc = (tid & 3) * 16;

    const int j0b = jbeg * 64;
    uint4 ka0 = *(const uint4*)(Kh + (size_t)(j0b + sr) * 64 + sc);
    uint4 ka1 = *(const uint4*)(Kh + (size_t)(j0b + sr) * 64 + sc + 8);
    uint4 va0 = *(const uint4*)(Vh + (size_t)sr * 2048 + j0b + sc);
    uint4 va1 = *(const uint4*)(Vh + (size_t)sr * 2048 + j0b + sc + 8);

    auto subtile = [&](int jt, int js, bool masked) {
        const int j0s = jt * 64 + js * 16;
        const float bj = -sl2 * (float)j0s;   // wave-uniform per subtile
        f32x4 sT = {};
        bf16x8 kf0 = *(const bf16x8*)(Ks + (js * 16 + l15) * 72 + quad * 8);
        bf16x8 kf1 = *(const bf16x8*)(Ks + (js * 16 + l15) * 72 + 32 + quad * 8);
        sT = MFMA_16x16x32(kf0, qf0, sT);
        sT = MFMA_16x16x32(kf1, qf1, sT);
        unsigned u[4];
        #pragma unroll
        for (int r = 0; r < 4; ++r) {
            float p = exp2f(fmaf(sT[r], c1, nb[r] + bj));
            if (masked && (j0s + quad * 4 + r) > i_) p = 0.0f;
            u[r] = __builtin_bit_cast(unsigned, p) + 0x8000u;
        }
        uint2 dd = { (u[0] >> 16) | (u[1] & 0xFFFF0000u),
                     (u[2] >> 16) | (u[3] & 0xFFFF0000u) };
        s4 pf = __builtin_bit_cast(s4, dd);
        accl = MFMA16(onesf, pf, accl);
        #pragma unroll
        for (int dt = 0; dt < 4; ++dt) {
            s4 vf = *(const s4*)(Vs + (dt * 16 + l15) * 72 + js * 16 + quad * 4);
            accv[dt] = MFMA16(vf, pf, accv[dt]);
        }
    };

    for (int jt = jbeg; jt < jend; ++jt) {
        __syncthreads();
        *(uint4*)(Ks + sr * 72 + sc)     = ka0;
        *(uint4*)(Ks + sr * 72 + sc + 8) = ka1;
        *(uint4*)(Vs + sr * 72 + sc)     = va0;
        *(uint4*)(Vs + sr * 72 + sc + 8) = va1;
        __syncthreads();
        if (jt + 1 < jend) {
            int j0n = (jt + 1) * 64;
            ka0 = *(const uint4*)(Kh + (size_t)(j0n + sr) * 64 + sc);
            ka1 = *(const uint4*)(Kh + (size_t)(j0n + sr) * 64 + sc + 8);
            va0 = *(const uint4*)(Vh + (size_t)sr * 2048 + j0n + sc);
            va1 = *(const uint4*)(Vh + (size_t)sr * 2048 + j0n + sc + 8);
        }
        if (jt < qb) {
            #pragma unroll
            for (int js = 0; js < 4; ++js) subtile(jt, js, false);
        } else {
            for (int js = 0; js < wv; ++js) subtile(jt, js, false);
            subtile(jt, wv, true);
        }
    }

    if (slot == 2047) {
        const float inv = 1.0f / fmaxf(accl[0], 1e-30f);
        const size_t obase = ((size_t)(b * 2048 + i_)) * 1024 + h * 64;
        #pragma unroll
        for (int dt = 0; dt < 4; ++dt) {
            ushort_t pk2[4];
            #pragma unroll
            for (int r = 0; r < 4; ++r) pk2[r] = f2bf(accv[dt][r] * inv);
            *(ushort2*)(AO + obase + dt * 16 + quad * 4)     = *(ushort2*)&pk2[0];
            *(ushort2*)(AO + obase + dt * 16 + quad * 4 + 2) = *(ushort2*)&pk2[2];
        }
    } else {
        const int rl = wv * 16 + l15;                   // local row 0..63
        float* pv = partV + ((size_t)slot * 64 + rl) * 64;
        #pragma unroll
        for (int dt = 0; dt < 4; ++dt)
            *(f32x4*)(pv + dt * 16 + quad * 4) = accv[dt];
        partL[slot * 64 + rl] = accl[0];

        // ---- fused last-chain merge (release/acquire via threadfence) ----
        const int mi_idx = g_sched.s2mi[slot];
        const unsigned info = g_sched.mi[mi_idx];
        const int cntv = (info >> 21) & 7;
        __threadfence();                 // release this block's partials
        __syncthreads();                 // all threads fenced before atomic
        if (tid == 0)
            s_last = (atomicAdd(&cntA[mi_idx], 1u) == (unsigned)(cntv - 1)) ? 1u : 0u;
        __syncthreads();
        if (s_last) {
            __threadfence();             // acquire other chains' partials
            const int base = (info >> 10) & 2047;
            const int bh2 = info & 31, qb2 = (info >> 5) & 31;
            const int b2 = bh2 >> 4, h2 = bh2 & 15;
            const int row = tid >> 2, cg = (tid & 3) * 16;
            float acc2[16] = {};
            float l = 0.0f;
            for (int c = 0; c < cntv; ++c) {
                const float* v = partV + ((size_t)(base + c) * 64 + row) * 64 + cg;
                #pragma unroll
                for (int j = 0; j < 16; ++j) acc2[j] += v[j];
                l += partL[(base + c) * 64 + row];
            }
            const float inv = 1.0f / fmaxf(l, 1e-30f);
            ushort_t pk2[16];
            #pragma unroll
            for (int j = 0; j < 16; ++j) pk2[j] = f2bf(acc2[j] * inv);
            const size_t o = ((size_t)(b2 * 2048 + qb2 * 64 + row)) * 1024 + h2 * 64 + cg;
            *(uint4*)(AO + o)     = *(uint4*)&pk2[0];
            *(uint4*)(AO + o + 8) = *(uint4*)&pk2[8];
        }
    }
}

// ---------------- Output projection GEMM + bias, 8-wave (R24) ----------------
__global__ __launch_bounds__(512) void oproj_gemm(
    const ushort_t* __restrict__ A, const ushort_t* __restrict__ WT,
    const ushort_t* __restrict__ bias, float* __restrict__ out)
{
    __shared__ ushort_t As[128 * 32];
    __shared__ ushort_t Bs[128 * 32];

    const int tid  = threadIdx.x;
    const int m0   = blockIdx.y * 128, n0 = blockIdx.x * 128;
    const int lane = tid & 63, wv = tid >> 6;           // wv 0..7
    const int quad = lane >> 4, l15 = lane & 15;
    const int wm = (wv >> 2) * 64;                      // 2 M-groups
    const int wn = (wv & 3) * 32;                       // 4 N-groups

    const int lrow = lane >> 2;
    const int schk = (lane & 3) ^ ((lane >> 3) & 3);
    const int ra0_ = wv * 16 + lrow;                    // 0..127 across 8 waves
    ushort_t* aB = As + wv * 512;                       // wave-uniform LDS bases
    ushort_t* bB = Bs + wv * 512;
    const int sp = quad ^ ((l15 >> 1) & 3);

    f32x4 acc[4][2] = {};

    for (int kt = 0; kt < 32; ++kt) {
        const int k0 = kt * 32;
        __syncthreads();
        gl_lds16(A  + (size_t)(m0 + ra0_) * 1024 + k0 + schk * 8, aB);
        gl_lds16(WT + (size_t)(n0 + ra0_) * 1024 + k0 + schk * 8, bB);
        __syncthreads();

        bf16x8 af[4], bfr[2];
        #pragma unroll
        for (int t = 0; t < 4; ++t)
            af[t]  = *(const bf16x8*)(As + (wm + t * 16 + l15) * 32 + sp * 8);
        #pragma unroll
        for (int u = 0; u < 2; ++u)
            bfr[u] = *(const bf16x8*)(Bs + (wn + u * 16 + l15) * 32 + sp * 8);
        #pragma unroll
        for (int mt = 0; mt < 4; ++mt)
            #pragma unroll
            for (int nt = 0; nt < 2; ++nt)
                acc[mt][nt] = MFMA_16x16x32(af[mt], bfr[nt], acc[mt][nt]);
    }

    #pragma unroll
    for (int mt = 0; mt < 4; ++mt) {
        #pragma unroll
        for (int nt = 0; nt < 2; ++nt) {
            #pragma unroll
            for (int r = 0; r < 4; ++r) {
                int m = m0 + wm + mt * 16 + quad * 4 + r;
                int c = n0 + wn + nt * 16 + l15;
                out[(size_t)m * 1024 + c] = acc[mt][nt][r] + bf2f(bias[c]);
            }
        }
    }
}

extern "C" void kernel_launch(void* const* d_in, const int* in_sizes, int n_in,
                              void* d_out, int out_size, void* d_ws, size_t ws_size,
                              hipStream_t stream) {
    const void* X  = d_in[0];
    const void* Wq = d_in[1];
    const void* Wk = d_in[2];
    const void* Wv = d_in[3];
    const void* Wo = d_in[4];
    const void* bo = d_in[5];

    const size_t M = 1024 * 1024;
    ushort_t* ws  = (ushort_t*)d_ws;
    ushort_t* Qb  = ws;
    ushort_t* Kb  = ws + 4 * M;
    ushort_t* Vt  = ws + 8 * M;
    ushort_t* Xc  = ws + 12 * M;    // shared with AO (Xc dead after qkv_gemm)
    ushort_t* AO  = ws + 12 * M;
    ushort_t* WqT = ws + 16 * M;
    ushort_t* WkT = ws + 17 * M;
    ushort_t* WvT = ws + 18 * M;
    ushort_t* WoT = ws + 19 * M;
    ushort_t* boc = ws + 20 * M;
    float* partV  = (float*)(ws + 22 * M);           // 1040*64*64 f32 (608 used)
    float* partL  = partV + (size_t)1040 * 64 * 64;  // 1040*64 f32
    unsigned* cntA = (unsigned*)(partL + 1040 * 64); // 240 merge counters
    float* out = (float*)d_out;

    prep<<<3073, 256, 0, stream>>>(X, Wq, Wk, Wv, Wo, bo, Xc, boc, WqT, WkT, WvT, WoT, cntA);
    qkv_gemm<<<dim3(8, 32, 3), 256, 0, stream>>>(Xc, WqT, WkT, WvT, Qb, Kb, Vt);
    attn_kernel<<<1536, 256, 0, stream>>>(Qb, Kb, Vt, AO, partV, partL, cntA);
    oproj_gemm<<<dim3(8, 32), 512, 0, stream>>>(AO, WoT, boc, out);
}

// Round 15
// 167.352 us; speedup vs baseline: 1.8636x; 1.8636x over previous
//
#include <hip/hip_runtime.h>
#include <hip/hip_bf16.h>

// B=2, N=2048, D=1024, H=16, DH=64. Output fp32; inputs runtime-detected and
// converted once. R12: qkv/oproj staging via global_load_lds width=16 + XOR
// chunk swizzle; attn diagonal-tile specialization.
// R14/R22/R25: attn ALiBi reach cap. R16/R18: XCD-grouped LPT schedule.
// R20/R21/R23 WINs (186.5->172.6): flash-decoding chain split (<=8 tiles) +
// exact f32 partial merge kernel; prep fusion; cap T=24.
// R22(b) REVERTED: direct-global K/V frags = 16 cachelines/lane-load.
// R25(b) REVERTED: fused last-chain merge -- __threadfence() = cross-XCD
// L2 writeback/invalidate per block (608x2 fences) nuked the K/V L2 working
// set for all running blocks; attn 20 -> 172us, MfmaUtil 2.5%. Cross-XCD
// producer-consumer inside one kernel is off the table (G16).
// R27 = R23 structure (separate atomics-free merge kernel) + T=16 cap
// (verified correct in R25 run: absmax 0.0078125): jcap
// [1,1,1,1,1,2,2,3,4,6,8,12,16,23,32,32], tiles 7578->6310 (0.83x);
// groups {775,800,806,774}; 1392 sub-items, worst XCD 176<=192, grid 1536;
// 240 merge items, 608 partial slots.
//
// ws (bf16 elems): Q@0(4M), K@4M, Vt@8M, Xc/AO@12M (shared), WqT@16M..WoT@19M,
// boc@20M, partials @22M (f32). ws >= 268MB per harness.

typedef __bf16 bf16x8 __attribute__((ext_vector_type(8)));
typedef float f32x4 __attribute__((ext_vector_type(4)));
typedef short s4 __attribute__((ext_vector_type(4)));      // k16 MFMA A/B frag
typedef unsigned short ushort_t;

#define MFMA_16x16x32(a, b, c) __builtin_amdgcn_mfma_f32_16x16x32_bf16(a, b, c, 0, 0, 0)
#define MFMA16(a, b, c) __builtin_amdgcn_mfma_f32_16x16x16bf16_1k(a, b, c, 0, 0, 0)

__device__ __forceinline__ ushort_t f2bf(float f) {
    __hip_bfloat16 h = __float2bfloat16(f);
    return __builtin_bit_cast(ushort_t, h);
}
__device__ __forceinline__ float bf2f(ushort_t u) {
    unsigned x = ((unsigned)u) << 16;
    return __builtin_bit_cast(float, x);
}

// async global->LDS, 16B/lane; LDS dest = wave-uniform base + lane*16.
__device__ __forceinline__ void gl_lds16(const ushort_t* g, ushort_t* l) {
    __builtin_amdgcn_global_load_lds(
        (const __attribute__((address_space(1))) void*)g,
        (__attribute__((address_space(3))) void*)l, 16, 0, 0);
}

__device__ __forceinline__ unsigned detect_fp32(const void* wp) {
    const ushort_t* w = (const ushort_t*)wp;
    unsigned c = 0;
    #pragma unroll
    for (int i = 0; i < 128; ++i) c += (((w[i] >> 7) & 0xFF) >= 0x7F) ? 1u : 0u;
    return (c > 8) ? 1u : 0u;
}

__device__ __forceinline__ uint4 load8(const void* p, size_t idx, unsigned flag) {
    if (flag) {
        const float* f = (const float*)p + idx;
        float4 a = *(const float4*)f;
        float4 b = *(const float4*)(f + 4);
        ushort_t u[8] = { f2bf(a.x), f2bf(a.y), f2bf(a.z), f2bf(a.w),
                          f2bf(b.x), f2bf(b.y), f2bf(b.z), f2bf(b.w) };
        return *(uint4*)u;
    }
    return *(const uint4*)((const ushort_t*)p + idx);
}

// ---- R27 schedule (T=16 cap). Sub-item encoding (32b):
// bh[4:0], qb[9:5], jbeg[14:10], jend[20:15], slot[31:21] (2047 = direct).
// e==0 marks empty slot. Merge item mi: bh[4:0], qb[9:5], base[20:10],
// cnt[23:21]. XCD = slot%8, CU = (slot/8)%32, round = slot/256.
// Items with w>=9 split into ceil(w/8) balanced chains (<=8 tiles).
struct Sched { unsigned v[1536]; unsigned mi[240]; };
constexpr Sched make_sched() {
    Sched s{};
    for (int i = 0; i < 1536; ++i) s.v[i] = 0;
    for (int i = 0; i < 240; ++i) s.mi[i] = 0;
    int jc[16] = {1, 1, 1, 1, 1, 2, 2, 3, 4, 6, 8, 12, 16, 23, 32, 32};
    // groups of 4 bh, tile-sums {775,800,806,774} per batch-group (T=16)
    int grp[8][4] = {
        {14, 8, 7, 0}, {15, 9, 5, 1}, {13, 10, 6, 2}, {12, 11, 4, 3},
        {16 + 14, 16 + 8, 16 + 7, 16 + 0}, {16 + 15, 16 + 9, 16 + 5, 16 + 1},
        {16 + 13, 16 + 10, 16 + 6, 16 + 2}, {16 + 12, 16 + 11, 16 + 4, 16 + 3},
    };
    int nslot = 0, nmi = 0;
    for (int x = 0; x < 8; ++x) {
        int sb_bh[256], sb_qb[256], sb_jb[256], sb_je[256], sb_sl[256];
        int n = 0;
        for (int gi = 0; gi < 4; ++gi) {
            int bh = grp[x][gi], h = bh & 15;
            for (int qb = 0; qb < 32; ++qb) {
                int w = (qb + 1 < jc[h]) ? (qb + 1) : jc[h];
                if (w >= 9) {
                    int nch = (w + 7) / 8;
                    s.mi[nmi++] = (unsigned)(bh | (qb << 5) | (nslot << 10) | (nch << 21));
                    int jb = 0;
                    for (int c = 0; c < nch; ++c) {
                        int je = jb + (w - jb) / (nch - c)
                               + (((w - jb) % (nch - c)) ? 1 : 0);
                        sb_bh[n] = bh; sb_qb[n] = qb; sb_jb[n] = jb;
                        sb_je[n] = je; sb_sl[n] = nslot++; ++n;
                        jb = je;
                    }
                } else {
                    sb_bh[n] = bh; sb_qb[n] = qb; sb_jb[n] = 0;
                    sb_je[n] = w; sb_sl[n] = 2047; ++n;
                }
            }
        }
        int m = 0;
        for (int w = 8; w >= 1; --w)                    // counting sort, desc len
            for (int i2 = 0; i2 < n; ++i2)
                if (sb_je[i2] - sb_jb[i2] == w) {
                    int t = m++;
                    int r = t >> 5, p = t & 31;
                    int cu = (r & 1) ? (31 - p) : p;    // serpentine
                    s.v[r * 256 + cu * 8 + x] = (unsigned)(
                        sb_bh[i2] | (sb_qb[i2] << 5) | (sb_jb[i2] << 10) |
                        (sb_je[i2] << 15) | (sb_sl[i2] << 21));
                }
    }
    return s;
}
__constant__ Sched g_sched = make_sched();

// ---------------- prep: convert X + bias + transpose weights (fused) ----------------
__global__ __launch_bounds__(256) void prep(
    const void* __restrict__ X, const void* __restrict__ Wq,
    const void* __restrict__ Wk, const void* __restrict__ Wv,
    const void* __restrict__ Wo, const void* __restrict__ bo,
    ushort_t* __restrict__ Xc, ushort_t* __restrict__ boc,
    ushort_t* __restrict__ WqT, ushort_t* __restrict__ WkT,
    ushort_t* __restrict__ WvT, ushort_t* __restrict__ WoT)
{
    __shared__ ushort_t T[64][72];
    const unsigned flag = detect_fp32(Wq);
    const int blk = blockIdx.x;
    if (blk < 2048) {
        size_t idx = (size_t)blk * 2048 + (size_t)threadIdx.x * 8;
        *(uint4*)(Xc + idx) = load8(X, idx, flag);
    } else if (blk == 2048) {
        size_t idx = (size_t)threadIdx.x * 8;
        if (idx < 1024) *(uint4*)(boc + idx) = load8(bo, idx, flag);
    } else {
        const int t = blk - 2049;                       // 0..1023
        const int z = t >> 8;
        const void* W = (z == 0) ? Wq : ((z == 1) ? Wk : ((z == 2) ? Wv : Wo));
        ushort_t* WT = (z == 0) ? WqT : ((z == 1) ? WkT : ((z == 2) ? WvT : WoT));
        const int k0 = ((t >> 4) & 15) * 64, n0 = (t & 15) * 64;
        const int r = threadIdx.x >> 2, c = (threadIdx.x & 3) * 16;

        *(uint4*)&T[r][c]     = load8(W, (size_t)(k0 + r) * 1024 + n0 + c,     flag);
        *(uint4*)&T[r][c + 8] = load8(W, (size_t)(k0 + r) * 1024 + n0 + c + 8, flag);
        __syncthreads();
        ushort_t tmp[16];
        #pragma unroll
        for (int j = 0; j < 16; ++j) tmp[j] = T[c + j][r];
        *(uint4*)(WT + (size_t)(n0 + r) * 1024 + k0 + c)     = *(uint4*)&tmp[0];
        *(uint4*)(WT + (size_t)(n0 + r) * 1024 + k0 + c + 8) = *(uint4*)&tmp[8];
    }
}

// ---------------- QKV projection GEMM, 128x128, global_load_lds staging ----------------
__global__ __launch_bounds__(256) void qkv_gemm(
    const ushort_t* __restrict__ X, const ushort_t* __restrict__ WqT,
    const ushort_t* __restrict__ WkT, const ushort_t* __restrict__ WvT,
    ushort_t* __restrict__ Q, ushort_t* __restrict__ K, ushort_t* __restrict__ Vt)
{
    __shared__ ushort_t As[128 * 32];
    __shared__ ushort_t Bs[128 * 32];

    const int z = blockIdx.z;
    const ushort_t* WT = (z == 0) ? WqT : ((z == 1) ? WkT : WvT);

    const int tid  = threadIdx.x;
    const int m0   = blockIdx.y * 128, n0 = blockIdx.x * 128;
    const int lane = tid & 63, wv = tid >> 6;
    const int quad = lane >> 4, l15 = lane & 15;
    const int wm = (wv & 1) * 64, wn = (wv >> 1) * 64;

    const int lrow = lane >> 2;                         // 0..15
    const int schk = (lane & 3) ^ ((lane >> 3) & 3);    // swizzled source chunk
    const int ra0_ = wv * 16 + lrow;                    // issue-0 row
    ushort_t* aB0 = As + wv * 512;                      // wave-uniform LDS bases
    ushort_t* aB1 = As + 2048 + wv * 512;
    ushort_t* bB0 = Bs + wv * 512;
    ushort_t* bB1 = Bs + 2048 + wv * 512;
    const int sp = quad ^ ((l15 >> 1) & 3);             // read chunk position

    f32x4 acc[4][4] = {};

    for (int kt = 0; kt < 32; ++kt) {
        const int k0 = kt * 32;
        __syncthreads();
        gl_lds16(X  + (size_t)(m0 + ra0_)      * 1024 + k0 + schk * 8, aB0);
        gl_lds16(X  + (size_t)(m0 + 64 + ra0_) * 1024 + k0 + schk * 8, aB1);
        gl_lds16(WT + (size_t)(n0 + ra0_)      * 1024 + k0 + schk * 8, bB0);
        gl_lds16(WT + (size_t)(n0 + 64 + ra0_) * 1024 + k0 + schk * 8, bB1);
        __syncthreads();   // compiler emits vmcnt(0) drain -> LDS data visible

        bf16x8 af[4], bfr[4];
        #pragma unroll
        for (int t = 0; t < 4; ++t) {
            af[t]  = *(const bf16x8*)(As + (wm + t * 16 + l15) * 32 + sp * 8);
            bfr[t] = *(const bf16x8*)(Bs + (wn + t * 16 + l15) * 32 + sp * 8);
        }
        #pragma unroll
        for (int mt = 0; mt < 4; ++mt)
            #pragma unroll
            for (int nt = 0; nt < 4; ++nt)
                acc[mt][nt] = MFMA_16x16x32(af[mt], bfr[nt], acc[mt][nt]);
    }

    #pragma unroll
    for (int mt = 0; mt < 4; ++mt) {
        #pragma unroll
        for (int nt = 0; nt < 4; ++nt) {
            if (z == 2) {
                int c  = n0 + wn + nt * 16 + l15;
                int h  = c >> 6, dh = c & 63;
                int mA = m0 + wm + mt * 16 + quad * 4;
                int b  = mA >> 11, nseq = mA & 2047;
                ushort_t pk[4];
                #pragma unroll
                for (int r = 0; r < 4; ++r) pk[r] = f2bf(acc[mt][nt][r]);
                *(ushort2*)(Vt + ((size_t)((b * 16 + h) * 64 + dh)) * 2048 + nseq)     = *(ushort2*)&pk[0];
                *(ushort2*)(Vt + ((size_t)((b * 16 + h) * 64 + dh)) * 2048 + nseq + 2) = *(ushort2*)&pk[2];
            } else {
                ushort_t* dst = (z == 0) ? Q : K;
                #pragma unroll
                for (int r = 0; r < 4; ++r) {
                    int m = m0 + wm + mt * 16 + quad * 4 + r;
                    int c = n0 + wn + nt * 16 + l15;
                    int b = m >> 11, nseq = m & 2047;
                    int h = c >> 6, dh = c & 63;
                    dst[((size_t)((b * 16 + h) * 2048 + nseq)) * 64 + dh] = f2bf(acc[mt][nt][r]);
                }
            }
        }
    }
}

// ---------------- MFMA flash attention: LDS-staged, <=8-tile chains ----------------
// grid 1536 flat, block 256 = 4 waves; sub-item from g_sched. slot==2047
// writes AO directly; else writes f32 partials (accv raw + accl) at slot.
// Partial sums are linear in j (softmax ref = j=0 globally) -> exact merge.
__global__ __launch_bounds__(256) void attn_kernel(
    const ushort_t* __restrict__ Q, const ushort_t* __restrict__ K,
    const ushort_t* __restrict__ Vt, ushort_t* __restrict__ AO,
    float* __restrict__ partV, float* __restrict__ partL)
{
    __shared__ ushort_t Ks[64 * 72];   // [j][d], stride 72
    __shared__ ushort_t Vs[64 * 72];   // [d][j], stride 72

    const unsigned e = g_sched.v[blockIdx.x];
    const int jend = (e >> 15) & 63;
    if (jend == 0) return;                              // empty slot

    const int tid  = threadIdx.x;
    const int wv   = tid >> 6, lane = tid & 63;
    const int quad = lane >> 4, l15 = lane & 15;
    const int bh   = e & 31, h = bh & 15, b = bh >> 4;
    const int qb   = (e >> 5) & 31;
    const int jbeg = (e >> 10) & 31;
    const int slot = (e >> 21) & 2047;
    const int iw   = qb * 64 + wv * 16;
    const int i_   = iw + l15;

    const ushort_t* Qh = Q  + (size_t)bh * 2048 * 64;
    const ushort_t* Kh = K  + (size_t)bh * 2048 * 64;
    const ushort_t* Vh = Vt + (size_t)bh * 64 * 2048;

    const float LOG2E = 1.44269504088896340736f;
    const float sl2 = exp2f(-0.5f * (float)(h + 1)) * LOG2E;
    const float c1  = 0.125f * LOG2E;

    bf16x8 qf0 = *(const bf16x8*)(Qh + (size_t)(iw + l15) * 64 + quad * 8);
    bf16x8 qf1 = *(const bf16x8*)(Qh + (size_t)(iw + l15) * 64 + 32 + quad * 8);

    s4 onesf;
    #pragma unroll
    for (int e2 = 0; e2 < 4; ++e2) onesf[e2] = (short)0x3F80;

    // per-lane bias base: -sl2*(quad*4+r); per-subtile only add -sl2*j0s.
    float nb[4];
    #pragma unroll
    for (int r = 0; r < 4; ++r) nb[r] = -sl2 * (float)(quad * 4 + r);

    f32x4 accv[4] = {};
    f32x4 accl = {};

    const int sr = tid >> 2, sc = (tid & 3) * 16;

    const int j0b = jbeg * 64;
    uint4 ka0 = *(const uint4*)(Kh + (size_t)(j0b + sr) * 64 + sc);
    uint4 ka1 = *(const uint4*)(Kh + (size_t)(j0b + sr) * 64 + sc + 8);
    uint4 va0 = *(const uint4*)(Vh + (size_t)sr * 2048 + j0b + sc);
    uint4 va1 = *(const uint4*)(Vh + (size_t)sr * 2048 + j0b + sc + 8);

    auto subtile = [&](int jt, int js, bool masked) {
        const int j0s = jt * 64 + js * 16;
        const float bj = -sl2 * (float)j0s;   // wave-uniform per subtile
        f32x4 sT = {};
        bf16x8 kf0 = *(const bf16x8*)(Ks + (js * 16 + l15) * 72 + quad * 8);
        bf16x8 kf1 = *(const bf16x8*)(Ks + (js * 16 + l15) * 72 + 32 + quad * 8);
        sT = MFMA_16x16x32(kf0, qf0, sT);
        sT = MFMA_16x16x32(kf1, qf1, sT);
        unsigned u[4];
        #pragma unroll
        for (int r = 0; r < 4; ++r) {
            float p = exp2f(fmaf(sT[r], c1, nb[r] + bj));
            if (masked && (j0s + quad * 4 + r) > i_) p = 0.0f;
            u[r] = __builtin_bit_cast(unsigned, p) + 0x8000u;
        }
        uint2 dd = { (u[0] >> 16) | (u[1] & 0xFFFF0000u),
                     (u[2] >> 16) | (u[3] & 0xFFFF0000u) };
        s4 pf = __builtin_bit_cast(s4, dd);
        accl = MFMA16(onesf, pf, accl);
        #pragma unroll
        for (int dt = 0; dt < 4; ++dt) {
            s4 vf = *(const s4*)(Vs + (dt * 16 + l15) * 72 + js * 16 + quad * 4);
            accv[dt] = MFMA16(vf, pf, accv[dt]);
        }
    };

    for (int jt = jbeg; jt < jend; ++jt) {
        __syncthreads();
        *(uint4*)(Ks + sr * 72 + sc)     = ka0;
        *(uint4*)(Ks + sr * 72 + sc + 8) = ka1;
        *(uint4*)(Vs + sr * 72 + sc)     = va0;
        *(uint4*)(Vs + sr * 72 + sc + 8) = va1;
        __syncthreads();
        if (jt + 1 < jend) {
            int j0n = (jt + 1) * 64;
            ka0 = *(const uint4*)(Kh + (size_t)(j0n + sr) * 64 + sc);
            ka1 = *(const uint4*)(Kh + (size_t)(j0n + sr) * 64 + sc + 8);
            va0 = *(const uint4*)(Vh + (size_t)sr * 2048 + j0n + sc);
            va1 = *(const uint4*)(Vh + (size_t)sr * 2048 + j0n + sc + 8);
        }
        if (jt < qb) {
            #pragma unroll
            for (int js = 0; js < 4; ++js) subtile(jt, js, false);
        } else {
            for (int js = 0; js < wv; ++js) subtile(jt, js, false);
            subtile(jt, wv, true);
        }
    }

    if (slot == 2047) {
        const float inv = 1.0f / fmaxf(accl[0], 1e-30f);
        const size_t obase = ((size_t)(b * 2048 + i_)) * 1024 + h * 64;
        #pragma unroll
        for (int dt = 0; dt < 4; ++dt) {
            ushort_t pk2[4];
            #pragma unroll
            for (int r = 0; r < 4; ++r) pk2[r] = f2bf(accv[dt][r] * inv);
            *(ushort2*)(AO + obase + dt * 16 + quad * 4)     = *(ushort2*)&pk2[0];
            *(ushort2*)(AO + obase + dt * 16 + quad * 4 + 2) = *(ushort2*)&pk2[2];
        }
    } else {
        const int rl = wv * 16 + l15;                   // local row 0..63
        float* pv = partV + ((size_t)slot * 64 + rl) * 64;
        #pragma unroll
        for (int dt = 0; dt < 4; ++dt)
            *(f32x4*)(pv + dt * 16 + quad * 4) = accv[dt];
        partL[slot * 64 + rl] = accl[0];
    }
}

// ---------------- merge partial chains -> AO ----------------
__global__ __launch_bounds__(256) void attn_merge(
    const float* __restrict__ partV, const float* __restrict__ partL,
    ushort_t* __restrict__ AO)
{
    const unsigned info = g_sched.mi[blockIdx.x];
    const int cnt = (info >> 21) & 7;
    if (cnt == 0) return;                               // unused entry guard
    const int bh = info & 31, qb = (info >> 5) & 31;
    const int base = (info >> 10) & 2047;
    const int b = bh >> 4, h = bh & 15;
    const int row = threadIdx.x >> 2, cg = (threadIdx.x & 3) * 16;

    float acc[16] = {};
    float l = 0.0f;
    for (int c = 0; c < cnt; ++c) {
        const float* v = partV + ((size_t)(base + c) * 64 + row) * 64 + cg;
        #pragma unroll
        for (int j = 0; j < 16; ++j) acc[j] += v[j];
        l += partL[(base + c) * 64 + row];
    }
    const float inv = 1.0f / fmaxf(l, 1e-30f);

    ushort_t pk2[16];
    #pragma unroll
    for (int j = 0; j < 16; ++j) pk2[j] = f2bf(acc[j] * inv);
    const size_t o = ((size_t)(b * 2048 + qb * 64 + row)) * 1024 + h * 64 + cg;
    *(uint4*)(AO + o)     = *(uint4*)&pk2[0];
    *(uint4*)(AO + o + 8) = *(uint4*)&pk2[8];
}

// ---------------- Output projection GEMM + bias, 8-wave (R24) ----------------
__global__ __launch_bounds__(512) void oproj_gemm(
    const ushort_t* __restrict__ A, const ushort_t* __restrict__ WT,
    const ushort_t* __restrict__ bias, float* __restrict__ out)
{
    __shared__ ushort_t As[128 * 32];
    __shared__ ushort_t Bs[128 * 32];

    const int tid  = threadIdx.x;
    const int m0   = blockIdx.y * 128, n0 = blockIdx.x * 128;
    const int lane = tid & 63, wv = tid >> 6;           // wv 0..7
    const int quad = lane >> 4, l15 = lane & 15;
    const int wm = (wv >> 2) * 64;                      // 2 M-groups
    const int wn = (wv & 3) * 32;                       // 4 N-groups

    const int lrow = lane >> 2;
    const int schk = (lane & 3) ^ ((lane >> 3) & 3);
    const int ra0_ = wv * 16 + lrow;                    // 0..127 across 8 waves
    ushort_t* aB = As + wv * 512;                       // wave-uniform LDS bases
    ushort_t* bB = Bs + wv * 512;
    const int sp = quad ^ ((l15 >> 1) & 3);

    f32x4 acc[4][2] = {};

    for (int kt = 0; kt < 32; ++kt) {
        const int k0 = kt * 32;
        __syncthreads();
        gl_lds16(A  + (size_t)(m0 + ra0_) * 1024 + k0 + schk * 8, aB);
        gl_lds16(WT + (size_t)(n0 + ra0_) * 1024 + k0 + schk * 8, bB);
        __syncthreads();

        bf16x8 af[4], bfr[2];
        #pragma unroll
        for (int t = 0; t < 4; ++t)
            af[t]  = *(const bf16x8*)(As + (wm + t * 16 + l15) * 32 + sp * 8);
        #pragma unroll
        for (int u = 0; u < 2; ++u)
            bfr[u] = *(const bf16x8*)(Bs + (wn + u * 16 + l15) * 32 + sp * 8);
        #pragma unroll
        for (int mt = 0; mt < 4; ++mt)
            #pragma unroll
            for (int nt = 0; nt < 2; ++nt)
                acc[mt][nt] = MFMA_16x16x32(af[mt], bfr[nt], acc[mt][nt]);
    }

    #pragma unroll
    for (int mt = 0; mt < 4; ++mt) {
        #pragma unroll
        for (int nt = 0; nt < 2; ++nt) {
            #pragma unroll
            for (int r = 0; r < 4; ++r) {
                int m = m0 + wm + mt * 16 + quad * 4 + r;
                int c = n0 + wn + nt * 16 + l15;
                out[(size_t)m * 1024 + c] = acc[mt][nt][r] + bf2f(bias[c]);
            }
        }
    }
}

extern "C" void kernel_launch(void* const* d_in, const int* in_sizes, int n_in,
                              void* d_out, int out_size, void* d_ws, size_t ws_size,
                              hipStream_t stream) {
    const void* X  = d_in[0];
    const void* Wq = d_in[1];
    const void* Wk = d_in[2];
    const void* Wv = d_in[3];
    const void* Wo = d_in[4];
    const void* bo = d_in[5];

    const size_t M = 1024 * 1024;
    ushort_t* ws  = (ushort_t*)d_ws;
    ushort_t* Qb  = ws;
    ushort_t* Kb  = ws + 4 * M;
    ushort_t* Vt  = ws + 8 * M;
    ushort_t* Xc  = ws + 12 * M;    // shared with AO (Xc dead after qkv_gemm)
    ushort_t* AO  = ws + 12 * M;
    ushort_t* WqT = ws + 16 * M;
    ushort_t* WkT = ws + 17 * M;
    ushort_t* WvT = ws + 18 * M;
    ushort_t* WoT = ws + 19 * M;
    ushort_t* boc = ws + 20 * M;
    float* partV  = (float*)(ws + 22 * M);           // 1040*64*64 f32 (608 used)
    float* partL  = partV + (size_t)1040 * 64 * 64;  // 1040*64 f32
    float* out = (float*)d_out;

    prep<<<3073, 256, 0, stream>>>(X, Wq, Wk, Wv, Wo, bo, Xc, boc, WqT, WkT, WvT, WoT);
    qkv_gemm<<<dim3(8, 32, 3), 256, 0, stream>>>(Xc, WqT, WkT, WvT, Qb, Kb, Vt);
    attn_kernel<<<1536, 256, 0, stream>>>(Qb, Kb, Vt, AO, partV, partL);
    attn_merge<<<240, 256, 0, stream>>>(partV, partL, AO);
    oproj_gemm<<<dim3(8, 32), 512, 0, stream>>>(AO, WoT, boc, out);
}